// Round 4
// baseline (612.534 us; speedup 1.0000x reference)
//
#include <hip/hip_runtime.h>
#include <hip/hip_bf16.h>

// MultiExpertLoRALinear on MI355X.
// Round 4: gemm -> 2-phase double-buffered pipeline with counted vmcnt (T3+T4,
//          raw s_barrier, never vmcnt(0) in loop); XCD swizzle reverted (R3:
//          FETCH 358->950MB regression); router_fused4 -> barrier-free, LDS-free
//          loop loading x directly in MFMA fragment layout.
// Pipeline:
//   convert_w3    : wh[o][KP] fp16 = [W_base | Bcat | 0]; vh[48][H] fp16.
//   router_fused4 : x -> fp16 (reg) -> xh main cols + z = x*vh^T via MFMA,
//                   softmax, c cols + zero pad of xh. No LDS/barriers in loop.
//   gemm          : fp16 MFMA GEMM [M, O, KP=4160], 128x128 tile, BK=64, dbuf
//                   LDS, XOR-swizzle (0 conflicts), stage-ahead + vmcnt(8).

typedef _Float16 f16x8 __attribute__((ext_vector_type(8)));
typedef float    f32x4 __attribute__((ext_vector_type(4)));

constexpr int H  = 4096;
constexpr int O  = 4096;
constexpr int KP = 4160;   // 4096 + 32 (c cols) + 32 zero pad
constexpr int EA = 4;
constexpr float SCALING_F = 2.0f;  // alpha/rank

typedef const __attribute__((address_space(1))) void gvoid;
typedef __attribute__((address_space(3))) void svoid;

__device__ inline void gload16(const void* g, void* s) {
  __builtin_amdgcn_global_load_lds((gvoid*)g, (svoid*)s, 16, 0, 0);
}

// ---------------------------------------------------------------------------
// Kernel 1: build wh and vh. Block o < O: wh row o. Block O+j: vh row j.
// ---------------------------------------------------------------------------
__global__ __launch_bounds__(256) void convert_w3_kernel(
    const float* __restrict__ W, const float* __restrict__ lora_B,
    const float* __restrict__ lora_A, const float* __restrict__ router_W,
    const int* __restrict__ active, _Float16* __restrict__ wh,
    _Float16* __restrict__ vh) {
  const int bid = blockIdx.x;
  const int tid = threadIdx.x;
  if (bid < O) {
    const int o = bid;
    const float* wrow = W + (size_t)o * H;
    _Float16* dstrow = wh + (size_t)o * KP;
    for (int g = tid; g < 520; g += 256) {
      const int k = g * 8;
      float v[8];
      if (k < H) {
        float4 a = *(const float4*)(wrow + k), b = *(const float4*)(wrow + k + 4);
        v[0] = a.x; v[1] = a.y; v[2] = a.z; v[3] = a.w;
        v[4] = b.x; v[5] = b.y; v[6] = b.z; v[7] = b.w;
      } else if (k < H + 32) {
        const int e = (k - H) >> 3;
        const float* s = lora_B + ((size_t)active[e] * O + o) * 8;  // [E,O,r]
        float4 a = *(const float4*)s, b = *(const float4*)(s + 4);
        v[0] = a.x; v[1] = a.y; v[2] = a.z; v[3] = a.w;
        v[4] = b.x; v[5] = b.y; v[6] = b.z; v[7] = b.w;
      } else {
#pragma unroll
        for (int i = 0; i < 8; ++i) v[i] = 0.f;
      }
      f16x8 h;
#pragma unroll
      for (int i = 0; i < 8; ++i) h[i] = (_Float16)v[i];
      *(f16x8*)(dstrow + k) = h;
    }
  } else {
    const int j = bid - O;          // 0..47
    const float* src = nullptr;
    if (j < 32)      src = lora_A + (size_t)(active[j >> 3] * 8 + (j & 7)) * H;
    else if (j < 36) src = router_W + (size_t)active[j - 32] * H;
    _Float16* dstrow = vh + (size_t)j * H;
    for (int g = tid; g < 512; g += 256) {
      const int k = g * 8;
      f16x8 h;
      if (src) {
        float4 a = *(const float4*)(src + k), b = *(const float4*)(src + k + 4);
        h[0] = (_Float16)a.x; h[1] = (_Float16)a.y;
        h[2] = (_Float16)a.z; h[3] = (_Float16)a.w;
        h[4] = (_Float16)b.x; h[5] = (_Float16)b.y;
        h[6] = (_Float16)b.z; h[7] = (_Float16)b.w;
      } else {
#pragma unroll
        for (int i = 0; i < 8; ++i) h[i] = (_Float16)0.f;
      }
      *(f16x8*)(dstrow + k) = h;
    }
  }
}

// ---------------------------------------------------------------------------
// Kernel 2: fused convert_x + router + c-columns. 256 thr = 4 waves,
// 16 tokens/block. Loads x DIRECTLY in MFMA A-frag layout: lane (r15,kg) reads
// x[t0+r15][kw + kg*8 .. +8] fp32 (4 lanes = 128B aligned segment -> same cache
// lines as coalesced). cvt in-reg -> xh write + MFMA vs vh B-frags read
// straight from global (vh = 384KB, L2-resident). No LDS, no barriers in loop.
// Wave w owns k-offset w*32 within each 128-chunk; cross-wave LDS reduce after.
// ---------------------------------------------------------------------------
__global__ __launch_bounds__(256) void router_fused4_kernel(
    const float* __restrict__ x, const _Float16* __restrict__ vh,
    const float* __restrict__ router_b, const float* __restrict__ prior,
    const int* __restrict__ active, _Float16* __restrict__ xh) {
  __shared__ float zred[4][16][48];
  const int tid  = threadIdx.x;
  const int lane = tid & 63;
  const int w    = tid >> 6;
  const long t0  = (long)blockIdx.x * 16;
  const int r15  = lane & 15;
  const int kg   = lane >> 4;

  const float*    xp  = x  + (t0 + r15) * H  + w * 32 + kg * 8;
  _Float16*       xhp = xh + (t0 + r15) * KP + w * 32 + kg * 8;
  const _Float16* vp  = vh + (size_t)r15 * H + w * 32 + kg * 8;

  f32x4 acc[3];
  const f32x4 zero = {0.f, 0.f, 0.f, 0.f};
  acc[0] = zero; acc[1] = zero; acc[2] = zero;

#pragma unroll 2
  for (int c = 0; c < 32; ++c) {
    const int ko = c * 128;
    float4 v0 = *(const float4*)(xp + ko);
    float4 v1 = *(const float4*)(xp + ko + 4);
    f16x8 a;
    a[0] = (_Float16)v0.x; a[1] = (_Float16)v0.y;
    a[2] = (_Float16)v0.z; a[3] = (_Float16)v0.w;
    a[4] = (_Float16)v1.x; a[5] = (_Float16)v1.y;
    a[6] = (_Float16)v1.z; a[7] = (_Float16)v1.w;
    *(f16x8*)(xhp + ko) = a;
#pragma unroll
    for (int nf = 0; nf < 3; ++nf) {
      f16x8 b = *(const f16x8*)(vp + (size_t)nf * 16 * H + ko);
      acc[nf] = __builtin_amdgcn_mfma_f32_16x16x32_f16(a, b, acc[nf], 0, 0, 0);
    }
  }

  // scatter partials: C/D layout col=lane&15 (j), row=(lane>>4)*4+r (token)
#pragma unroll
  for (int nf = 0; nf < 3; ++nf)
#pragma unroll
    for (int r = 0; r < 4; ++r)
      zred[w][kg * 4 + r][nf * 16 + r15] = acc[nf][r];
  __syncthreads();

  // reduce 4 wave-partials: 16*48 = 768 slots, 3 per thread
  float s[3];
#pragma unroll
  for (int j = 0; j < 3; ++j) {
    const int sl = tid + 256 * j;
    const int tt = sl / 48, jj = sl % 48;
    s[j] = zred[0][tt][jj] + zred[1][tt][jj] + zred[2][tt][jj] + zred[3][tt][jj];
  }
  __syncthreads();
#pragma unroll
  for (int j = 0; j < 3; ++j) {
    const int sl = tid + 256 * j;
    zred[0][sl / 48][sl % 48] = s[j];
  }
  __syncthreads();

  // softmax + c-columns + zero pad: thread = (token tt, expert e)
  if (tid < 16 * EA) {
    const int tt = tid >> 2, e = tid & 3;
    const float* zt = &zred[0][tt][0];
    float le[EA], mx = -1e30f;
#pragma unroll
    for (int e2 = 0; e2 < EA; ++e2) {
      const int ae = active[e2];
      le[e2] = logf(prior[ae] + 1e-12f) + zt[32 + e2] + router_b[ae];
      mx = fmaxf(mx, le[e2]);
    }
    float sum = 0.f;
#pragma unroll
    for (int e2 = 0; e2 < EA; ++e2) sum += expf(le[e2] - mx);
    const float a = expf(le[e] - mx) / sum * SCALING_F;
    f16x8 ch, zz;
#pragma unroll
    for (int r = 0; r < 8; ++r) {
      ch[r] = (_Float16)(a * zt[e * 8 + r]);
      zz[r] = (_Float16)0.f;
    }
    _Float16* xr = xh + (t0 + tt) * KP + H;
    *(f16x8*)(xr + e * 8) = ch;
    *(f16x8*)(xr + 32 + e * 8) = zz;
  }
}

// ---------------------------------------------------------------------------
// Kernel 3: fp16 MFMA GEMM, 2-phase double-buffered (T3+T4).
// out[t][o] = sum_k xh[t][k]*wh[o][k] + b_base[o].
// Loop: stage(t+1 -> buf^1); s_waitcnt vmcnt(8) [tile t landed, t+1 in flight];
// raw s_barrier; compute tile t (32 MFMA/wave); raw s_barrier.
// Race-free: buf^1's readers (tile t-1 compute) passed the trailing barrier
// before this iteration's stage issues. vmcnt never drains to 0 in the loop.
// ---------------------------------------------------------------------------
constexpr int BM = 128, BN = 128, BK = 64, NT = KP / BK;  // 65 tiles

__global__ __launch_bounds__(256) void gemm_kernel(
    const _Float16* __restrict__ xh, const _Float16* __restrict__ wh,
    const float* __restrict__ b_base, float* __restrict__ out) {
  __shared__ _Float16 As[2][BM * BK];   // 2 x 16 KB
  __shared__ _Float16 Ws[2][BN * BK];   // 2 x 16 KB
  const int tid  = threadIdx.x;
  const int lane = tid & 63;
  const int wave = tid >> 6;
  const int bid  = (int)blockIdx.x;
  const int im = bid >> 5;                 // 64 M-tiles
  const int in = bid & 31;                 // 32 N-tiles
  const size_t trow0 = (size_t)im * BM;
  const size_t ocol0 = (size_t)in * BN;
  const int wr = wave >> 1, wc = wave & 1;

  f32x4 acc[4][4];
  const f32x4 zero = {0.f, 0.f, 0.f, 0.f};
#pragma unroll
  for (int m = 0; m < 4; ++m)
#pragma unroll
    for (int n = 0; n < 4; ++n) acc[m][n] = zero;

  const int srow  = lane >> 3;
  const int sslot = (lane & 7) ^ srow;     // pre-swizzled global slot
  const int r15 = lane & 15;
  const int kg  = lane >> 4;

  // stage one K-tile into buffer b: 8 gload16/thread (wave-uniform LDS base)
  auto stage = [&](int b, int t) {
    const int k0 = t * BK;
#pragma unroll
    for (int i = 0; i < 8; ++i) {
      const int ch  = wave + 4 * i;        // 0..31 ; <16 = A region, else W
      const int sub = ch & 15;
      const int row = sub * 8 + srow;
      if (ch < 16)
        gload16(xh + (trow0 + row) * KP + k0 + sslot * 8, &As[b][sub * 512]);
      else
        gload16(wh + (ocol0 + row) * KP + k0 + sslot * 8, &Ws[b][sub * 512]);
    }
  };

  stage(0, 0);                             // prologue: tile 0 in flight (8)
  for (int t = 0; t < NT; ++t) {
    const int b = t & 1;
    if (t + 1 < NT) {
      stage(b ^ 1, t + 1);                 // 8 more in flight
      asm volatile("s_waitcnt vmcnt(8)" ::: "memory");   // tile t landed
    } else {
      asm volatile("s_waitcnt vmcnt(0)" ::: "memory");   // last tile: drain
    }
    __builtin_amdgcn_s_barrier();
#pragma unroll
    for (int kk = 0; kk < 2; ++kk) {
      f16x8 a[4], bfr[4];
#pragma unroll
      for (int m = 0; m < 4; ++m) {
        const int row  = wr * 64 + m * 16 + r15;
        const int slot = (kk * 4 + kg) ^ (row & 7);
        a[m] = *(const f16x8*)(&As[b][row * 64 + slot * 8]);
      }
#pragma unroll
      for (int n = 0; n < 4; ++n) {
        const int row  = wc * 64 + n * 16 + r15;
        const int slot = (kk * 4 + kg) ^ (row & 7);
        bfr[n] = *(const f16x8*)(&Ws[b][row * 64 + slot * 8]);
      }
#pragma unroll
      for (int m = 0; m < 4; ++m)
#pragma unroll
        for (int n = 0; n < 4; ++n)
          acc[m][n] = __builtin_amdgcn_mfma_f32_16x16x32_f16(a[m], bfr[n], acc[m][n], 0, 0, 0);
    }
    __builtin_amdgcn_s_barrier();          // readers done before next overwrite
  }

  // epilogue: C/D layout col=lane&15 (o), row=(lane>>4)*4+j (token)
#pragma unroll
  for (int n = 0; n < 4; ++n) {
    const size_t col = ocol0 + wc * 64 + n * 16 + r15;
    const float bb = b_base[col];
#pragma unroll
    for (int m = 0; m < 4; ++m) {
      const size_t row = trow0 + wr * 64 + m * 16 + kg * 4;
#pragma unroll
      for (int j = 0; j < 4; ++j)
        out[(row + j) * O + col] = acc[m][n][j] + bb;
    }
  }
}

// ---------------------------------------------------------------------------
extern "C" void kernel_launch(void* const* d_in, const int* in_sizes, int n_in,
                              void* d_out, int out_size, void* d_ws, size_t ws_size,
                              hipStream_t stream) {
  const float* x        = (const float*)d_in[0];
  const float* W_base   = (const float*)d_in[1];
  const float* b_base   = (const float*)d_in[2];
  const float* lora_A   = (const float*)d_in[3];
  const float* lora_B   = (const float*)d_in[4];
  const float* router_W = (const float*)d_in[5];
  const float* router_b = (const float*)d_in[6];
  const float* prior    = (const float*)d_in[7];
  const int*   active   = (const int*)d_in[8];
  float* out = (float*)d_out;

  const int M = in_sizes[0] / H;  // 8192 tokens

  char* ws = (char*)d_ws;
  _Float16* xh = (_Float16*)ws;                               // M*KP*2  = 68.2 MB
  _Float16* wh = (_Float16*)(ws + (size_t)M * KP * 2);        // O*KP*2  = 34.1 MB
  _Float16* vh = (_Float16*)(ws + (size_t)M * KP * 2 + (size_t)O * KP * 2);  // 384 KB

  convert_w3_kernel<<<O + 48, 256, 0, stream>>>(W_base, lora_B, lora_A, router_W,
                                                active, wh, vh);
  router_fused4_kernel<<<M / 16, 256, 0, stream>>>(x, vh, router_b, prior, active, xh);
  gemm_kernel<<<(M / BM) * (O / BN), 256, 0, stream>>>(xh, wh, b_base, out);
}

// Round 5
// 592.950 us; speedup vs baseline: 1.0330x; 1.0330x over previous
//
#include <hip/hip_runtime.h>
#include <hip/hip_bf16.h>

// MultiExpertLoRALinear on MI355X.
// Round 5: gemm reverted to validated R2 single-buffer structure (R4's 2-phase
//          counted-vmcnt regressed: VALUBusy 16->45%, the documented T3/T4-
//          without-8-phase null). router_fused5: 1024-thr blocks (16 waves,
//          K-slice 256/wave, fully unrolled) -> 2x occupancy + deep ILP.
// Pipeline:
//   convert_w3    : wh[o][KP] fp16 = [W_base | Bcat | 0]; vh[48][H] fp16.
//   router_fused5 : x -> fp16 (reg) -> xh main cols + z = x*vh^T via MFMA,
//                   16-wave in-block reduce, softmax, c cols + zero pad.
//   gemm          : fp16 MFMA GEMM [M, O, KP=4160], 128x128 tile, BK=64,
//                   single-buffer LDS, XOR-swizzle (0 conflicts measured),
//                   global_load_lds staging. (R2-validated: 312 us, 894 TF.)

typedef _Float16 f16x8 __attribute__((ext_vector_type(8)));
typedef float    f32x4 __attribute__((ext_vector_type(4)));

constexpr int H  = 4096;
constexpr int O  = 4096;
constexpr int KP = 4160;   // 4096 + 32 (c cols) + 32 zero pad
constexpr int EA = 4;
constexpr float SCALING_F = 2.0f;  // alpha/rank

typedef const __attribute__((address_space(1))) void gvoid;
typedef __attribute__((address_space(3))) void svoid;

__device__ inline void gload16(const void* g, void* s) {
  __builtin_amdgcn_global_load_lds((gvoid*)g, (svoid*)s, 16, 0, 0);
}

// ---------------------------------------------------------------------------
// Kernel 1: build wh and vh. Block o < O: wh row o. Block O+j: vh row j.
// ---------------------------------------------------------------------------
__global__ __launch_bounds__(256) void convert_w3_kernel(
    const float* __restrict__ W, const float* __restrict__ lora_B,
    const float* __restrict__ lora_A, const float* __restrict__ router_W,
    const int* __restrict__ active, _Float16* __restrict__ wh,
    _Float16* __restrict__ vh) {
  const int bid = blockIdx.x;
  const int tid = threadIdx.x;
  if (bid < O) {
    const int o = bid;
    const float* wrow = W + (size_t)o * H;
    _Float16* dstrow = wh + (size_t)o * KP;
    for (int g = tid; g < 520; g += 256) {
      const int k = g * 8;
      float v[8];
      if (k < H) {
        float4 a = *(const float4*)(wrow + k), b = *(const float4*)(wrow + k + 4);
        v[0] = a.x; v[1] = a.y; v[2] = a.z; v[3] = a.w;
        v[4] = b.x; v[5] = b.y; v[6] = b.z; v[7] = b.w;
      } else if (k < H + 32) {
        const int e = (k - H) >> 3;
        const float* s = lora_B + ((size_t)active[e] * O + o) * 8;  // [E,O,r]
        float4 a = *(const float4*)s, b = *(const float4*)(s + 4);
        v[0] = a.x; v[1] = a.y; v[2] = a.z; v[3] = a.w;
        v[4] = b.x; v[5] = b.y; v[6] = b.z; v[7] = b.w;
      } else {
#pragma unroll
        for (int i = 0; i < 8; ++i) v[i] = 0.f;
      }
      f16x8 h;
#pragma unroll
      for (int i = 0; i < 8; ++i) h[i] = (_Float16)v[i];
      *(f16x8*)(dstrow + k) = h;
    }
  } else {
    const int j = bid - O;          // 0..47
    const float* src = nullptr;
    if (j < 32)      src = lora_A + (size_t)(active[j >> 3] * 8 + (j & 7)) * H;
    else if (j < 36) src = router_W + (size_t)active[j - 32] * H;
    _Float16* dstrow = vh + (size_t)j * H;
    for (int g = tid; g < 512; g += 256) {
      const int k = g * 8;
      f16x8 h;
      if (src) {
        float4 a = *(const float4*)(src + k), b = *(const float4*)(src + k + 4);
        h[0] = (_Float16)a.x; h[1] = (_Float16)a.y;
        h[2] = (_Float16)a.z; h[3] = (_Float16)a.w;
        h[4] = (_Float16)b.x; h[5] = (_Float16)b.y;
        h[6] = (_Float16)b.z; h[7] = (_Float16)b.w;
      } else {
#pragma unroll
        for (int i = 0; i < 8; ++i) h[i] = (_Float16)0.f;
      }
      *(f16x8*)(dstrow + k) = h;
    }
  }
}

// ---------------------------------------------------------------------------
// Kernel 2: fused convert_x + router + c-columns. 1024 thr = 16 waves,
// 16 tokens/block; wave w owns K-slice [w*256, w*256+256) (8 MFMA k-windows,
// fully unrolled). Lane (r15,kg) loads x[t0+r15][...] directly in MFMA A-frag
// layout (4 lanes = 128B segment), cvt in-reg, writes xh, MFMAs vs vh B-frags
// read straight from global (vh 384KB, L2-resident). 16-wave LDS reduce,
// softmax, c cols + zero pad. 16 waves/CU resident (2x R4's occupancy).
// ---------------------------------------------------------------------------
constexpr int RW5 = 16;   // waves per block

__global__ __launch_bounds__(1024) void router_fused5_kernel(
    const float* __restrict__ x, const _Float16* __restrict__ vh,
    const float* __restrict__ router_b, const float* __restrict__ prior,
    const int* __restrict__ active, _Float16* __restrict__ xh) {
  __shared__ float zred[RW5][16][48];   // 48 KB
  const int tid  = threadIdx.x;
  const int lane = tid & 63;
  const int w    = tid >> 6;            // 0..15
  const long t0  = (long)blockIdx.x * 16;
  const int r15  = lane & 15;
  const int kg   = lane >> 4;

  const float*    xp  = x  + (t0 + r15) * H  + w * 256 + kg * 8;
  _Float16*       xhp = xh + (t0 + r15) * KP + w * 256 + kg * 8;
  const _Float16* vp  = vh + (size_t)r15 * H + w * 256 + kg * 8;

  f32x4 acc[3];
  const f32x4 zero = {0.f, 0.f, 0.f, 0.f};
  acc[0] = zero; acc[1] = zero; acc[2] = zero;

#pragma unroll
  for (int c = 0; c < 8; ++c) {
    const int ko = c * 32;
    float4 v0 = *(const float4*)(xp + ko);
    float4 v1 = *(const float4*)(xp + ko + 4);
    f16x8 a;
    a[0] = (_Float16)v0.x; a[1] = (_Float16)v0.y;
    a[2] = (_Float16)v0.z; a[3] = (_Float16)v0.w;
    a[4] = (_Float16)v1.x; a[5] = (_Float16)v1.y;
    a[6] = (_Float16)v1.z; a[7] = (_Float16)v1.w;
    *(f16x8*)(xhp + ko) = a;
#pragma unroll
    for (int nf = 0; nf < 3; ++nf) {
      f16x8 b = *(const f16x8*)(vp + (size_t)nf * 16 * H + ko);
      acc[nf] = __builtin_amdgcn_mfma_f32_16x16x32_f16(a, b, acc[nf], 0, 0, 0);
    }
  }

  // scatter partials: C/D layout col=lane&15 (j), row=(lane>>4)*4+r (token)
#pragma unroll
  for (int nf = 0; nf < 3; ++nf)
#pragma unroll
    for (int r = 0; r < 4; ++r)
      zred[w][kg * 4 + r][nf * 16 + r15] = acc[nf][r];
  __syncthreads();

  // reduce 16 wave-partials: 768 slots, one per thread (tid < 768)
  float s = 0.f;
  int tt = 0, jj = 0;
  if (tid < 16 * 48) {
    tt = tid / 48; jj = tid % 48;
#pragma unroll
    for (int ww = 0; ww < RW5; ++ww) s += zred[ww][tt][jj];
  }
  __syncthreads();
  if (tid < 16 * 48) zred[0][tt][jj] = s;
  __syncthreads();

  // softmax + c-columns + zero pad: thread = (token tt, expert e)
  if (tid < 16 * EA) {
    const int t2 = tid >> 2, e = tid & 3;
    const float* zt = &zred[0][t2][0];
    float le[EA], mx = -1e30f;
#pragma unroll
    for (int e2 = 0; e2 < EA; ++e2) {
      const int ae = active[e2];
      le[e2] = logf(prior[ae] + 1e-12f) + zt[32 + e2] + router_b[ae];
      mx = fmaxf(mx, le[e2]);
    }
    float sum = 0.f;
#pragma unroll
    for (int e2 = 0; e2 < EA; ++e2) sum += expf(le[e2] - mx);
    const float a = expf(le[e] - mx) / sum * SCALING_F;
    f16x8 ch, zz;
#pragma unroll
    for (int r = 0; r < 8; ++r) {
      ch[r] = (_Float16)(a * zt[e * 8 + r]);
      zz[r] = (_Float16)0.f;
    }
    _Float16* xr = xh + (t0 + t2) * KP + H;
    *(f16x8*)(xr + e * 8) = ch;
    *(f16x8*)(xr + 32 + e * 8) = zz;
  }
}

// ---------------------------------------------------------------------------
// Kernel 3: fp16 MFMA GEMM (R2-validated structure).
// out[t][o] = sum_k xh[t][k]*wh[o][k] + b_base[o].
// 128x128 tile, BK=64, 4 waves x (64x64), single-buffer LDS, XOR swizzle,
// global_load_lds staging.
// ---------------------------------------------------------------------------
constexpr int BM = 128, BN = 128, BK = 64;

__global__ __launch_bounds__(256) void gemm_kernel(
    const _Float16* __restrict__ xh, const _Float16* __restrict__ wh,
    const float* __restrict__ b_base, float* __restrict__ out) {
  __shared__ _Float16 As[BM * BK];
  __shared__ _Float16 Ws[BN * BK];
  const int tid  = threadIdx.x;
  const int lane = tid & 63;
  const int wave = tid >> 6;
  const int im = (int)(blockIdx.x >> 5);   // 64 M-tiles
  const int in = (int)(blockIdx.x & 31);   // 32 N-tiles
  const size_t trow0 = (size_t)im * BM;
  const size_t ocol0 = (size_t)in * BN;
  const int wr = wave >> 1, wc = wave & 1;

  f32x4 acc[4][4];
  const f32x4 zero = {0.f, 0.f, 0.f, 0.f};
#pragma unroll
  for (int m = 0; m < 4; ++m)
#pragma unroll
    for (int n = 0; n < 4; ++n) acc[m][n] = zero;

  const int srow  = lane >> 3;
  const int sslot = (lane & 7) ^ srow;     // pre-swizzled global slot
  const int r15 = lane & 15;
  const int kg  = lane >> 4;

  for (int step = 0; step < KP / BK; ++step) {   // 65 steps
    const int k0 = step * BK;
    __syncthreads();
#pragma unroll
    for (int i = 0; i < 8; ++i) {
      const int ch  = wave + 4 * i;        // 0..31 ; <16 = A region, else W
      const int sub = ch & 15;
      const int row = sub * 8 + srow;
      if (ch < 16)
        gload16(xh + (trow0 + row) * KP + k0 + sslot * 8, As + sub * 512);
      else
        gload16(wh + (ocol0 + row) * KP + k0 + sslot * 8, Ws + sub * 512);
    }
    __syncthreads();
#pragma unroll
    for (int kk = 0; kk < 2; ++kk) {
      f16x8 a[4], b[4];
#pragma unroll
      for (int m = 0; m < 4; ++m) {
        const int row  = wr * 64 + m * 16 + r15;
        const int slot = (kk * 4 + kg) ^ (row & 7);
        a[m] = *(const f16x8*)(As + row * 64 + slot * 8);
      }
#pragma unroll
      for (int n = 0; n < 4; ++n) {
        const int row  = wc * 64 + n * 16 + r15;
        const int slot = (kk * 4 + kg) ^ (row & 7);
        b[n] = *(const f16x8*)(Ws + row * 64 + slot * 8);
      }
#pragma unroll
      for (int m = 0; m < 4; ++m)
#pragma unroll
        for (int n = 0; n < 4; ++n)
          acc[m][n] = __builtin_amdgcn_mfma_f32_16x16x32_f16(a[m], b[n], acc[m][n], 0, 0, 0);
    }
  }
  // epilogue: C/D layout col=lane&15 (o), row=(lane>>4)*4+j (token)
#pragma unroll
  for (int n = 0; n < 4; ++n) {
    const size_t col = ocol0 + wc * 64 + n * 16 + r15;
    const float bb = b_base[col];
#pragma unroll
    for (int m = 0; m < 4; ++m) {
      const size_t row = trow0 + wr * 64 + m * 16 + kg * 4;
#pragma unroll
      for (int j = 0; j < 4; ++j)
        out[(row + j) * O + col] = acc[m][n][j] + bb;
    }
  }
}

// ---------------------------------------------------------------------------
extern "C" void kernel_launch(void* const* d_in, const int* in_sizes, int n_in,
                              void* d_out, int out_size, void* d_ws, size_t ws_size,
                              hipStream_t stream) {
  const float* x        = (const float*)d_in[0];
  const float* W_base   = (const float*)d_in[1];
  const float* b_base   = (const float*)d_in[2];
  const float* lora_A   = (const float*)d_in[3];
  const float* lora_B   = (const float*)d_in[4];
  const float* router_W = (const float*)d_in[5];
  const float* router_b = (const float*)d_in[6];
  const float* prior    = (const float*)d_in[7];
  const int*   active   = (const int*)d_in[8];
  float* out = (float*)d_out;

  const int M = in_sizes[0] / H;  // 8192 tokens

  char* ws = (char*)d_ws;
  _Float16* xh = (_Float16*)ws;                               // M*KP*2  = 68.2 MB
  _Float16* wh = (_Float16*)(ws + (size_t)M * KP * 2);        // O*KP*2  = 34.1 MB
  _Float16* vh = (_Float16*)(ws + (size_t)M * KP * 2 + (size_t)O * KP * 2);  // 384 KB

  convert_w3_kernel<<<O + 48, 256, 0, stream>>>(W_base, lora_B, lora_A, router_W,
                                                active, wh, vh);
  router_fused5_kernel<<<M / 16, 1024, 0, stream>>>(x, vh, router_b, prior, active, xh);
  gemm_kernel<<<(M / BM) * (O / BN), 256, 0, stream>>>(xh, wh, b_base, out);
}